// Round 10
// baseline (182.537 us; speedup 1.0000x reference)
//
#include <hip/hip_runtime.h>
#include <stdint.h>

// Problem constants
#define Bsz 4096
#define Tn  64      // scan length (char_seq[:, :-1])
#define T1n 65
#define Hn  64
#define Pn  50
#define Vn  32

typedef __attribute__((ext_vector_type(8))) short short8;
typedef __attribute__((ext_vector_type(4))) short short4v;
typedef __attribute__((ext_vector_type(4))) float floatx4;

__device__ __forceinline__ float bf2f(unsigned short u) {
  union { unsigned int i; float f; } x; x.i = ((unsigned int)u) << 16; return x.f;
}
__device__ __forceinline__ unsigned short f2bf(float f) {
  union { float f; unsigned int i; } x; x.f = f;
  return (unsigned short)((x.i + 0x7FFFu + ((x.i >> 16) & 1u)) >> 16);
}
__device__ __forceinline__ float fast_sigmoid(float x) {
  return __builtin_amdgcn_rcpf(1.f + __expf(-x));
}
__device__ __forceinline__ float fast_tanh(float x) {
  return 1.f - 2.f * __builtin_amdgcn_rcpf(1.f + __expf(2.f * x));
}

// W^T A-operand fragment: A[m=lane&15][k=quad*8+j] = W[k][col16 + m]
// (identical register content to the old B-frag gather)
__device__ __forceinline__ short8 load_bfrag(const float* __restrict__ W, int ncols, int col, int kbase) {
  short8 f;
#pragma unroll
  for (int j = 0; j < 8; ++j) f[j] = (short)f2bf(W[(long)(kbase + j) * ncols + col]);
  return f;
}

// Producer/consumer fused GRU, transposed MFMA orientation (W^T as A, h^T as B).
// 256 blocks x 512 threads (8 waves). Block owns 16 batch rows. C-layout now
// (row = out-col q*4+reg, col = batch c16): each lane holds 4 consecutive
// hidden cols of ONE batch row -> all transpose writes are single b64s, TBL
// lookups are single b64s (cr depends only on the lane's batch row).
// Waves 0-3 (scan): r-gate (A) + c-gate/h-update (B) for col tile w.
// Waves 4-7 (aux): z-gate in A (b128 -> z_s); waves 4-5 project h_{t-1} in B.
// Chunk tails every 8 steps (single vmcnt drain per chunk).
__launch_bounds__(512)
__global__ void gru_kernel(const float* __restrict__ phon,
                           const int* __restrict__ cs,
                           const float* __restrict__ emb,
                           const float* __restrict__ Wrx, const float* __restrict__ brx,
                           const float* __restrict__ Wrh, const float* __restrict__ brh,
                           const float* __restrict__ Wzx, const float* __restrict__ bzx,
                           const float* __restrict__ Wzh, const float* __restrict__ bzh,
                           const float* __restrict__ Whx, const float* __restrict__ bhx,
                           const float* __restrict__ Whh, const float* __restrict__ bhh,
                           const float* __restrict__ Wpj, const float* __restrict__ bpj_g,
                           float* __restrict__ ws,
                           float* __restrict__ outp) {
  __shared__ unsigned short tbl_s[3 * 2112];                 // bf16 [g][v][66]
  __shared__ __align__(16) unsigned short hist_s[8 * 1152];  // bf16 h[t&7][bat][72]
  __shared__ __align__(16) unsigned short rh_s[1152];        // bf16 r*h [bat][72]
  __shared__ __align__(16) float z_s[16 * 68];               // f32 z [bat][68]
  __shared__ __align__(16) float logit_s[8 * 576];           // f32 [page][bat][36]
  __shared__ unsigned char code_s[16 * 68];                  // [bat][t], t=0..64
  __shared__ int det_s[1];
  __shared__ float red_s[16];

  const int tid = threadIdx.x;
  const int b0 = blockIdx.x * 16;
  const int W8 = tid >> 6, lane = tid & 63, q = lane >> 4, c16 = lane & 15;
  const bool isScan = (W8 < 4);
  const int w = isScan ? W8 : (W8 - 4);
  const int jcol = w * 16 + c16;   // A-frag column (out-dim)
  const int jc4 = w * 16 + q * 4;  // this lane's 4-col group (out-dim)
  const floatx4 zf = {0.f, 0.f, 0.f, 0.f};

  // --- int32-vs-int64 detection for char_seq ---
  if (tid == 0) det_s[0] = 0;
  __syncthreads();
  if (tid < 128 && cs[2 * tid + 1] != 0) atomicOr(&det_s[0], 1);
  __syncthreads();
  const bool is64 = (det_s[0] == 0);

  // --- staging ---
  for (int i = tid; i < 1152; i += 512) hist_s[7 * 1152 + i] = 0;   // h0 slot
  for (int i = tid; i < 16 * T1n; i += 512) {
    int m = i / T1n, t = i - m * T1n;
    long idx = (long)(b0 + m) * T1n + t;
    int c = is64 ? cs[2 * idx] : cs[idx];
    code_s[m * 68 + t] = (unsigned char)c;
  }

  // --- TBL: tbl_s[g][v][j] = bf16( emb[v] @ W_gx[:64] + b_gx[j] + b_gh[j] ) ---
  // wave W8 handles v = W8 + 8k (emb reads wave-uniform -> scalar loads)
  for (int g = 0; g < 3; ++g) {
    const float* Wg = (g == 0) ? Wrx : (g == 1) ? Wzx : Whx;
    const float* bx = (g == 0) ? brx : (g == 1) ? bzx : bhx;
    const float* bh = (g == 0) ? brh : (g == 1) ? bzh : bhh;
    float acc[4] = {0.f, 0.f, 0.f, 0.f};
    float bias = bx[lane] + bh[lane];
    for (int d = 0; d < Hn; ++d) {
      float wv = Wg[(long)d * Hn + lane];
#pragma unroll
      for (int k = 0; k < 4; ++k)
        acc[k] += emb[(long)(W8 + 8 * k) * Hn + d] * wv;
    }
#pragma unroll
    for (int k = 0; k < 4; ++k)
      tbl_s[g * 2112 + (W8 + 8 * k) * 66 + lane] = f2bf(acc[k] + bias);
  }

  // --- PH per-lane: batch c16, cols jc4..jc4+3 ---
  float ph_a[4] = {0.f, 0.f, 0.f, 0.f};  // scan: r-gate | aux: z-gate
  float ph_h[4] = {0.f, 0.f, 0.f, 0.f};  // scan only
  {
    const float* Wa = isScan ? Wrx : Wzx;
    for (int p = 0; p < Pn; ++p) {
      float xv = phon[(long)(b0 + c16) * Pn + p];
      floatx4 wa4 = *(const floatx4*)&Wa[(long)(Hn + p) * Hn + jc4];
#pragma unroll
      for (int r = 0; r < 4; ++r) ph_a[r] += xv * wa4[r];
      if (isScan) {
        floatx4 wh4 = *(const floatx4*)&Whx[(long)(Hn + p) * Hn + jc4];
#pragma unroll
        for (int r = 0; r < 4; ++r) ph_h[r] += xv * wh4[r];
      }
    }
  }

  // --- A-operand fragments (W^T, register-resident, t-invariant) ---
  short8 Ba0, Ba1;   // scan: W_rh | aux: W_zh
  short8 Bh0, Bh1;   // scan: W_hh
  short8 Bp0, Bp1;   // waves 4,5: W_proj (vocab tile vt)
  floatx4 bpj4 = zf;
  const int vt = W8 - 4;
  {
    const float* Wa = isScan ? Wrh : Wzh;
    Ba0 = load_bfrag(Wa, Hn, jcol, q * 8);
    Ba1 = load_bfrag(Wa, Hn, jcol, 32 + q * 8);
    Bh0 = Ba0; Bh1 = Ba1; Bp0 = Ba0; Bp1 = Ba1;
    if (isScan) {
      Bh0 = load_bfrag(Whh, Hn, jcol, q * 8);
      Bh1 = load_bfrag(Whh, Hn, jcol, 32 + q * 8);
    } else if (W8 < 6) {
      Bp0 = load_bfrag(Wpj, Vn, vt * 16 + c16, q * 8);
      Bp1 = load_bfrag(Wpj, Vn, vt * 16 + c16, 32 + q * 8);
      bpj4 = *(const floatx4*)&bpj_g[vt * 16 + q * 4];
    }
  }

  float h[4] = {0.f, 0.f, 0.f, 0.f};
  float nll = 0.f, cnt = 0.f;
  unsigned int cw = 0;

  __syncthreads();   // prologue done

  for (int t = 0; t < Tn; ++t) {
    if ((t & 3) == 0) cw = *(const unsigned int*)&code_s[c16 * 68 + t];
    const int crb = (cw >> ((t & 3) * 8)) & 255;   // batch c16's code at t

    // ===== interval A =====
    const unsigned short* hp = &hist_s[((t + 7) & 7) * 1152];
    short8 hb0 = *(const short8*)&hp[c16 * 72 + q * 8];
    short8 hb1 = *(const short8*)&hp[c16 * 72 + 32 + q * 8];
    if (isScan) {       // r-gate -> rh_s (one b64 write)
      floatx4 acc = __builtin_amdgcn_mfma_f32_16x16x32_bf16(Ba0, hb0, zf, 0, 0, 0);
      acc = __builtin_amdgcn_mfma_f32_16x16x32_bf16(Ba1, hb1, acc, 0, 0, 0);
      short4v tr = *(const short4v*)&tbl_s[0 * 2112 + crb * 66 + jc4];
      short4v rhp;
#pragma unroll
      for (int r = 0; r < 4; ++r) {
        float xr = bf2f((unsigned short)tr[r]) + ph_a[r] + acc[r];
        rhp[r] = (short)f2bf(fast_sigmoid(xr) * h[r]);
      }
      *(short4v*)&rh_s[c16 * 72 + jc4] = rhp;
    } else {            // z-gate -> z_s (one b128 write)
      floatx4 acc = __builtin_amdgcn_mfma_f32_16x16x32_bf16(Ba0, hb0, zf, 0, 0, 0);
      acc = __builtin_amdgcn_mfma_f32_16x16x32_bf16(Ba1, hb1, acc, 0, 0, 0);
      short4v tz = *(const short4v*)&tbl_s[1 * 2112 + crb * 66 + jc4];
      floatx4 z4;
#pragma unroll
      for (int r = 0; r < 4; ++r)
        z4[r] = fast_sigmoid(bf2f((unsigned short)tz[r]) + ph_a[r] + acc[r]);
      *(floatx4*)&z_s[c16 * 68 + jc4] = z4;
    }
    __syncthreads();  // A

    // ===== interval B =====
    if (isScan) {       // c-gate + h-update -> hist_s[t&7] (one b64 write)
      short8 p0 = *(const short8*)&rh_s[c16 * 72 + q * 8];
      short8 p1 = *(const short8*)&rh_s[c16 * 72 + 32 + q * 8];
      floatx4 acc = __builtin_amdgcn_mfma_f32_16x16x32_bf16(Bh0, p0, zf, 0, 0, 0);
      acc = __builtin_amdgcn_mfma_f32_16x16x32_bf16(Bh1, p1, acc, 0, 0, 0);
      short4v th = *(const short4v*)&tbl_s[2 * 2112 + crb * 66 + jc4];
      floatx4 z4 = *(const floatx4*)&z_s[c16 * 68 + jc4];
      short4v hb4;
#pragma unroll
      for (int r = 0; r < 4; ++r) {
        float xh = bf2f((unsigned short)th[r]) + ph_h[r] + acc[r];
        float c = fast_tanh(xh);
        float hn = (1.f - z4[r]) * h[r] + z4[r] * c;
        h[r] = hn;
        hb4[r] = (short)f2bf(hn);
      }
      *(short4v*)&hist_s[(t & 7) * 1152 + c16 * 72 + jc4] = hb4;
    } else if (W8 < 6 && t > 0) {   // project h_{t-1} (hb0/hb1 reused from A)
      floatx4 l = __builtin_amdgcn_mfma_f32_16x16x32_bf16(Bp0, hb0, zf, 0, 0, 0);
      l = __builtin_amdgcn_mfma_f32_16x16x32_bf16(Bp1, hb1, l, 0, 0, 0);
      floatx4 lg4;
#pragma unroll
      for (int r = 0; r < 4; ++r) lg4[r] = l[r] + bpj4[r];
      *(floatx4*)&logit_s[((t - 1) & 7) * 576 + c16 * 36 + vt * 16 + q * 4] = lg4;
    }
    __syncthreads();  // B

    // ===== chunk tail: every 8 steps, all 8 waves =====
    if ((t & 7) == 7) {
      int p = t - 8 + W8;           // pages t-8 .. t-1
      if (p >= 0) {
        const float* pg = &logit_s[(p & 7) * 576];
        int v = lane & 31, hf = lane >> 5;
#pragma unroll
        for (int i = 0; i < 8; ++i) {
          int m = i * 2 + hf;
          float lg = pg[m * 36 + v];
          float s = __expf(lg);
#pragma unroll
          for (int off = 16; off >= 1; off >>= 1) s += __shfl_xor(s, off);
          float lse = __logf(s);     // |logits| <= ~8, safe without max-sub
          outp[(((long)(b0 + m)) * Tn + p) * Vn + v] = lg;
          int targ = code_s[m * 68 + p + 1];
          if (targ != 0 && v == targ) { nll += lse - lg; cnt += 1.f; }
        }
      }
    }
  }

  // ===== epilogue: project + finalize t = 63 =====
  __syncthreads();
  if (W8 >= 4 && W8 < 6) {
    const unsigned short* hp = &hist_s[7 * 1152];   // h_63
    short8 a0 = *(const short8*)&hp[c16 * 72 + q * 8];
    short8 a1 = *(const short8*)&hp[c16 * 72 + 32 + q * 8];
    floatx4 l = __builtin_amdgcn_mfma_f32_16x16x32_bf16(Bp0, a0, zf, 0, 0, 0);
    l = __builtin_amdgcn_mfma_f32_16x16x32_bf16(Bp1, a1, l, 0, 0, 0);
    floatx4 lg4;
#pragma unroll
    for (int r = 0; r < 4; ++r) lg4[r] = l[r] + bpj4[r];
    *(floatx4*)&logit_s[7 * 576 + c16 * 36 + vt * 16 + q * 4] = lg4;
  }
  __syncthreads();
  if (W8 == 0) {
    const float* pg = &logit_s[7 * 576];
    int v = lane & 31, hf = lane >> 5;
#pragma unroll
    for (int i = 0; i < 8; ++i) {
      int m = i * 2 + hf;
      float lg = pg[m * 36 + v];
      float s = __expf(lg);
#pragma unroll
      for (int off = 16; off >= 1; off >>= 1) s += __shfl_xor(s, off);
      float lse = __logf(s);
      outp[(((long)(b0 + m)) * Tn + 63) * Vn + v] = lg;
      int targ = code_s[m * 68 + 64];
      if (targ != 0 && v == targ) { nll += lse - lg; cnt += 1.f; }
    }
  }

  // ===== reduction -> per-block ws slot =====
#pragma unroll
  for (int off = 32; off >= 1; off >>= 1) {
    nll += __shfl_xor(nll, off);
    cnt += __shfl_xor(cnt, off);
  }
  if (lane == 0) { red_s[W8] = nll; red_s[8 + W8] = cnt; }
  __syncthreads();
  if (tid == 0) {
    float n = 0.f, c = 0.f;
#pragma unroll
    for (int i = 0; i < 8; ++i) { n += red_s[i]; c += red_s[8 + i]; }
    ws[2 * blockIdx.x] = n;
    ws[2 * blockIdx.x + 1] = c;
  }
}

__global__ void loss_kernel(const float* __restrict__ ws, float* __restrict__ outp) {
  int lane = threadIdx.x;  // 64 threads
  float n = 0.f, c = 0.f;
  for (int i = lane; i < Bsz / 16; i += 64) { n += ws[2 * i]; c += ws[2 * i + 1]; }
#pragma unroll
  for (int off = 32; off >= 1; off >>= 1) {
    n += __shfl_xor(n, off);
    c += __shfl_xor(c, off);
  }
  if (lane == 0) outp[(size_t)Bsz * Tn * Vn] = n / fmaxf(c, 1.f);
}

extern "C" void kernel_launch(void* const* d_in, const int* in_sizes, int n_in,
                              void* d_out, int out_size, void* d_ws, size_t ws_size,
                              hipStream_t stream) {
  const float* phon = (const float*)d_in[0];
  const int*   cs   = (const int*)d_in[1];
  const float* emb  = (const float*)d_in[2];
  const float* Wrx  = (const float*)d_in[3];
  const float* brx  = (const float*)d_in[4];
  const float* Wrh  = (const float*)d_in[5];
  const float* brh  = (const float*)d_in[6];
  const float* Wzx  = (const float*)d_in[7];
  const float* bzx  = (const float*)d_in[8];
  const float* Wzh  = (const float*)d_in[9];
  const float* bzh  = (const float*)d_in[10];
  const float* Whx  = (const float*)d_in[11];
  const float* bhx  = (const float*)d_in[12];
  const float* Whh  = (const float*)d_in[13];
  const float* bhh  = (const float*)d_in[14];
  const float* Wpj  = (const float*)d_in[15];
  const float* bpj  = (const float*)d_in[16];
  float* ws = (float*)d_ws;

  hipLaunchKernelGGL(gru_kernel, dim3(Bsz / 16), dim3(512), 0, stream,
                     phon, cs, emb, Wrx, brx, Wrh, brh, Wzx, bzx, Wzh, bzh,
                     Whx, bhx, Whh, bhh, Wpj, bpj, ws, (float*)d_out);
  hipLaunchKernelGGL(loss_kernel, dim3(1), dim3(64), 0, stream, ws, (float*)d_out);
}